// Round 4
// baseline (233.888 us; speedup 1.0000x reference)
//
#include <hip/hip_runtime.h>
#include <math.h>

// GaussianSpot: out[1,B,F,14,14] = bg[b,f] + sum_k h/(2*pi*w^2) * exp(-((i-sx)^2+(j-sy)^2)/(2w^2))
// Separable Gaussian, fused single kernel.
//   phase 1 (registers): thread = (AOI p, quarter q). 36 exp2f -> ex[k][4] (coef folded),
//            ey[k][14]; 49 pixels with constexpr-unrolled indices -> LDS image buffer.
//   phase 2: pure LDS->global non-temporal float4 streaming copy.
// R3 deltas vs R2: 32 AOIs/block + 128 threads (25 KB LDS -> 6 blocks/CU, smaller barrier
// domain, more independent store streams), nontemporal stores (out is write-once),
// float2 gather of target_locs. f32x4 = ext_vector_type (HIP float4 class rejected by
// __builtin_nontemporal_store).
// Write-BW floor: 205.5 MB out -> ~33 us at 6.3 TB/s.

#define DD 14
#define BB 512
#define FFRAMES 512
#define NF_TAB 1024
#define PAIRS 32
#define BLOCK 128
#define IMG (DD * DD)   // 196 (divisible by 4: float4 never crosses AOI boundary)

typedef float f32x4 __attribute__((ext_vector_type(4)));

__global__ __launch_bounds__(BLOCK) void gauss_spot_kernel(
    const float* __restrict__ height, const float* __restrict__ width,
    const float* __restrict__ xoff, const float* __restrict__ yoff,
    const float* __restrict__ background, const float* __restrict__ target_locs,
    const int* __restrict__ n_idx, const int* __restrict__ f_tab,
    float* __restrict__ out)
{
    __shared__ float img[PAIRS * IMG];   // 25088 B -> 6 blocks/CU

    const int tid = threadIdx.x;
    const int p = tid >> 2;              // AOI within block (0..31)
    const int q = tid & 3;               // quarter: pixels [49q, 49q+49)
    const int pair = blockIdx.x * PAIRS + p;   // b*F + fi
    const int b = pair >> 9;             // F = 512
    const int fi = pair & (FFRAMES - 1);

    // early scalar/index prefetch
    const int n = n_idx[b];              // n_idx is [B,1]
    const int ff = f_tab[fi];
    const float2 loc = ((const float2*)target_locs)[n * NF_TAB + ff];  // (sx_base, sy_base)
    const float bg = background[pair];

    // i range for this quarter: q=0 -> 0..3, q=1 -> 3..6, q=2 -> 7..10, q=3 -> 10..13
    const int i_lo = (49 * q) / 14;

    float ex[2][4], ey[2][14];
    #pragma unroll
    for (int k = 0; k < 2; ++k) {
        const int idx = k * (BB * FFRAMES) + pair;
        const float w = width[idx];
        const float h = height[idx];
        const float sx = loc.x + xoff[idx];
        const float sy = loc.y + yoff[idx];
        const float inv2w2 = 1.0f / (2.0f * w * w);
        const float coef = h * inv2w2 * 0.31830988618379067f;  // h/(2*pi*w^2)
        const float a = inv2w2 * 1.4426950408889634f;          // log2(e)/(2w^2)
        #pragma unroll
        for (int t = 0; t < 4; ++t) {
            float d = (float)(i_lo + t) - sx;
            ex[k][t] = coef * exp2f(-d * d * a);
        }
        #pragma unroll
        for (int j = 0; j < 14; ++j) {
            float d = (float)j - sy;
            ey[k][j] = exp2f(-d * d * a);
        }
    }

    // compute 49 pixels; il/j are compile-time after unroll (parity branch).
    float* dst = img + p * IMG + 49 * q;
    if (q & 1) {
        #pragma unroll
        for (int e = 0; e < 49; ++e) {
            const int il = (7 + e) / 14, j = (7 + e) % 14;
            dst[e] = bg + ex[0][il] * ey[0][j] + ex[1][il] * ey[1][j];
        }
    } else {
        #pragma unroll
        for (int e = 0; e < 49; ++e) {
            const int il = e / 14, j = e % 14;
            dst[e] = bg + ex[0][il] * ey[0][j] + ex[1][il] * ey[1][j];
        }
    }
    __syncthreads();

    // phase 2: streaming LDS -> global, non-temporal coalesced float4.
    const f32x4* src4 = (const f32x4*)img;
    f32x4* out4 = (f32x4*)(out + (size_t)blockIdx.x * (PAIRS * IMG));
    const int NV = PAIRS * IMG / 4;   // 1568 = 12*128 + 32
    #pragma unroll
    for (int it = 0; it < 12; ++it) {
        const int v = tid + it * BLOCK;
        __builtin_nontemporal_store(src4[v], &out4[v]);
    }
    if (tid < NV - 12 * BLOCK) {
        const int v = tid + 12 * BLOCK;
        __builtin_nontemporal_store(src4[v], &out4[v]);
    }
}

extern "C" void kernel_launch(void* const* d_in, const int* in_sizes, int n_in,
                              void* d_out, int out_size, void* d_ws, size_t ws_size,
                              hipStream_t stream) {
    const float* height      = (const float*)d_in[0];
    const float* width       = (const float*)d_in[1];
    const float* x           = (const float*)d_in[2];
    const float* y           = (const float*)d_in[3];
    const float* background  = (const float*)d_in[4];
    const float* target_locs = (const float*)d_in[5];
    const int*   n_idx       = (const int*)d_in[6];
    const int*   f           = (const int*)d_in[7];
    float* out = (float*)d_out;

    const int total_pairs = BB * FFRAMES;          // 262144
    const int grid = total_pairs / PAIRS;          // 8192
    gauss_spot_kernel<<<grid, BLOCK, 0, stream>>>(
        height, width, x, y, background, target_locs, n_idx, f, out);
}